// Round 12
// baseline (21555.798 us; speedup 1.0000x reference)
//
#include <hip/hip_runtime.h>
#include <hip/hip_bf16.h>

#define S_LEN 4096
#define IDIM  2048
#define HDIM  2048
#define G4    8192
#define NB    256
#define TPB   512
#define SENT  0x7FC00000u   // qNaN: h = sigmoid*tanh of finite data, never NaN

typedef __attribute__((ext_vector_type(2))) float  f32x2;
typedef __attribute__((ext_vector_type(4))) float  f32x4;
typedef __attribute__((ext_vector_type(8))) short  bf16x8;

// packed fp32 FMA: acc += w*h (2 MACs/instruction)
#define PKFMA(acc, w, h) \
  asm("v_pk_fma_f32 %0, %1, %2, %0" : "+v"(acc) : "v"(w), "v"(h))

// ---- bf16 helpers ----
__device__ __forceinline__ unsigned short f2bf(float f) {
  unsigned u = __float_as_uint(f);
  unsigned r = (u + 0x7FFFu + ((u >> 16) & 1u)) >> 16;   // RNE
  return (unsigned short)r;
}
__device__ __forceinline__ float bf2f(unsigned short h) {
  return __uint_as_float(((unsigned)h) << 16);
}
__device__ __forceinline__ f32x2 bfpair(unsigned u) {    // 2 packed bf16 -> f32x2
  f32x2 r;
  r.x = __uint_as_float(u << 16);
  r.y = __uint_as_float(u & 0xFFFF0000u);
  return r;
}
__device__ __forceinline__ f32x2 mk2(float a, float b) {
  f32x2 r; r.x = a; r.y = b; return r;
}
__device__ __forceinline__ float sigmoid_fast(float x) {
  return __builtin_amdgcn_rcpf(1.f + __expf(-x));
}
__device__ __forceinline__ float tanh_fast(float x) {
  return 1.f - 2.f * __builtin_amdgcn_rcpf(__expf(2.f * x) + 1.f);
}

// =====================================================================
// Kernel 0: fill out with sentinel (per-element readiness ground state)
// =====================================================================
__global__ __launch_bounds__(256) void fill_sentinel(unsigned long long* p) {
  const unsigned long long v =
      ((unsigned long long)SENT << 32) | (unsigned long long)SENT;
  const int n = S_LEN * HDIM / 2;
  for (int i = blockIdx.x * 256 + threadIdx.x; i < n; i += gridDim.x * 256)
    p[i] = v;
}

// =====================================================================
// Kernel 1: xg = x·W_ihᵀ + b_ih + b_hh, bf16 MFMA. (proven, ~0.1 ms)
// =====================================================================
#define BM 128
#define BKK 32
#define LDK 40

__global__ __launch_bounds__(256) void gemm_xg_mfma(
    const float* __restrict__ x, const float* __restrict__ Wih,
    const float* __restrict__ bih, const float* __restrict__ bhh,
    unsigned short* __restrict__ xg) {
  __shared__ unsigned short As[BM][LDK];
  __shared__ unsigned short Bs[BM][LDK];

  const int t = threadIdx.x;
  const int lane = t & 63, wid = t >> 6;
  const int wr = wid >> 1, wc = wid & 1;

  int bid = ((int)blockIdx.x & 7) * 256 + ((int)blockIdx.x >> 3);
  const int s0 = (bid >> 6) * BM;
  const int j0 = (bid & 63) * BM;

  f32x4 acc[4][4] = {};

  float bias[4];
#pragma unroll
  for (int n = 0; n < 4; ++n) {
    const int col = j0 + wc * 64 + n * 16 + (lane & 15);
    bias[n] = bih[col] + bhh[col];
  }

  for (int k0 = 0; k0 < IDIM; k0 += BKK) {
    float4 va[4], vb[4];
#pragma unroll
    for (int u = 0; u < 4; ++u) {
      const int f = t + 256 * u;
      const int row = f >> 3, kc = (f & 7) * 4;
      va[u] = *(const float4*)&x  [(size_t)(s0 + row) * IDIM + k0 + kc];
      vb[u] = *(const float4*)&Wih[(size_t)(j0 + row) * IDIM + k0 + kc];
    }
    __syncthreads();
#pragma unroll
    for (int u = 0; u < 4; ++u) {
      const int f = t + 256 * u;
      const int row = f >> 3, kc = (f & 7) * 4;
      ushort4 pa, pb;
      pa.x = f2bf(va[u].x); pa.y = f2bf(va[u].y);
      pa.z = f2bf(va[u].z); pa.w = f2bf(va[u].w);
      pb.x = f2bf(vb[u].x); pb.y = f2bf(vb[u].y);
      pb.z = f2bf(vb[u].z); pb.w = f2bf(vb[u].w);
      *(ushort4*)&As[row][kc] = pa;
      *(ushort4*)&Bs[row][kc] = pb;
    }
    __syncthreads();

    const int fr = lane & 15, koff = (lane >> 4) * 8;
    bf16x8 a[4], bfr[4];
#pragma unroll
    for (int m = 0; m < 4; ++m)
      a[m] = *(const bf16x8*)&As[wr * 64 + m * 16 + fr][koff];
#pragma unroll
    for (int n = 0; n < 4; ++n)
      bfr[n] = *(const bf16x8*)&Bs[wc * 64 + n * 16 + fr][koff];
#pragma unroll
    for (int m = 0; m < 4; ++m)
#pragma unroll
      for (int n = 0; n < 4; ++n)
        acc[m][n] = __builtin_amdgcn_mfma_f32_16x16x32_bf16(
            a[m], bfr[n], acc[m][n], 0, 0, 0);
  }

#pragma unroll
  for (int m = 0; m < 4; ++m) {
    const int row0 = s0 + wr * 64 + m * 16 + (lane >> 4) * 4;
#pragma unroll
    for (int n = 0; n < 4; ++n) {
      const int col = j0 + wc * 64 + n * 16 + (lane & 15);
#pragma unroll
      for (int r = 0; r < 4; ++r)
        xg[(size_t)(row0 + r) * G4 + col] = f2bf(acc[m][n][r] + bias[n]);
    }
  }
}

// =====================================================================
// Kernel 2: persistent scan — LDS-resident bf16 weights, CONSUMED AT
// USE (the r1-r11 lesson: hipcc will not hold a large per-thread weight
// cache — array/named/pinned/AGPR all spill, remat, or serialize. So
// keep live ranges tiny: load one uint4, use it in 4 pk_fma, move on;
// ~32 VGPRs live => nothing to spill, ds_read_b128 is the intended,
// cheap re-access).
//  k-map: lane l covers k = i*512 + 8l + e (e<8, i<4).
//  W LDS: ushort (wid*4+g)*2048 + i*512 + l*8  — 16B/lane contiguous.
//  h LDS: hA (e<4) / hB (e>=4), f32 i*256 + l*4 — 16B/lane contiguous.
//  SYNC (r6, measured best): publish 4B h store -> raw s_barrier ->
//  flag store; wave0 polls 256 flags; all threads bulk-read h with
//  per-element qNaN-sentinel retry; two __syncthreads.
// =====================================================================

#define LDW(g, i) \
  (*(const uint4*)&Wlds[(wid * 4 + (g)) * 2048 + (i) * 512 + lane * 8])

#define DGC(Acc, W, HA, HB) do { \
  PKFMA(Acc, bfpair(W.x), mk2(HA.x, HA.y)); \
  PKFMA(Acc, bfpair(W.y), mk2(HA.z, HA.w)); \
  PKFMA(Acc, bfpair(W.z), mk2(HB.x, HB.y)); \
  PKFMA(Acc, bfpair(W.w), mk2(HB.z, HB.w)); \
} while (0)

__global__ __launch_bounds__(TPB, 1) void lstm_scan(
    const unsigned short* __restrict__ xg, const float* __restrict__ Whh,
    const float* __restrict__ h0, const float* __restrict__ c0,
    float* __restrict__ out, unsigned* __restrict__ flags) {
  extern __shared__ unsigned short Wlds[];    // 128 KB dynamic
  __shared__ __align__(16) float hA[1024];    // e in 0..3 of each 8-k granule
  __shared__ __align__(16) float hB[1024];    // e in 4..7

  const int b = blockIdx.x, t = threadIdx.x;
  const int lane = t & 63, wid = t >> 6;
  const int j = b * 8 + wid;                  // this wave's unit

  // ---- one-time: weights -> LDS (bf16), lane-contiguous rows ----
#pragma unroll
  for (int g = 0; g < 4; ++g) {
    const float* wp = Whh + ((size_t)g * HDIM + j) * HDIM;
#pragma unroll
    for (int i = 0; i < 4; ++i) {
      const float4 q0 = *(const float4*)(wp + i * 512 + lane * 8);
      const float4 q1 = *(const float4*)(wp + i * 512 + lane * 8 + 4);
      uint4 pk;
      pk.x = (unsigned)f2bf(q0.x) | ((unsigned)f2bf(q0.y) << 16);
      pk.y = (unsigned)f2bf(q0.z) | ((unsigned)f2bf(q0.w) << 16);
      pk.z = (unsigned)f2bf(q1.x) | ((unsigned)f2bf(q1.y) << 16);
      pk.w = (unsigned)f2bf(q1.z) | ((unsigned)f2bf(q1.w) << 16);
      *(uint4*)&Wlds[(wid * 4 + g) * 2048 + i * 512 + lane * 8] = pk;
    }
  }

  // stage h0: k = i*512 + 8l + e -> hA/hB[i*256 + l*4 + (e&3)]
#pragma unroll
  for (int kk = 0; kk < 4; ++kk) {
    const int k = t + kk * 512;
    const float v = h0[k];
    const int i = k >> 9, r = (k >> 3) & 63, e = k & 7;
    (((e & 4) ? hB : hA) + i * 256 + r * 4)[e & 3] = v;
  }
  __syncthreads();                            // weights + h0 staged

  float c_reg = (lane == 0) ? c0[j] : 0.f;

  for (int ts = 0; ts < S_LEN; ++ts) {
    // xg prefetch (lanes 0-3: this unit's 4 gate pre-activations)
    float xgv = 0.f;
    if (lane < 4)
      xgv = bf2f(xg[(size_t)ts * G4 + (size_t)lane * HDIM + j]);

    // ---- dot: per granule, 2 h-reads + 4 w-reads + 16 pk_fma.
    // Live range ~32 VGPRs — nothing to spill, compiler pipelines.
    f32x2 A0 = {0.f, 0.f}, A1 = {0.f, 0.f}, A2 = {0.f, 0.f}, A3 = {0.f, 0.f};
#pragma unroll
    for (int i = 0; i < 4; ++i) {
      const f32x4 ha = *(const f32x4*)&hA[i * 256 + lane * 4];
      const f32x4 hb = *(const f32x4*)&hB[i * 256 + lane * 4];
      const uint4 w0 = LDW(0, i);
      const uint4 w1 = LDW(1, i);
      const uint4 w2 = LDW(2, i);
      const uint4 w3 = LDW(3, i);
      DGC(A0, w0, ha, hb);
      DGC(A1, w1, ha, hb);
      DGC(A2, w2, ha, hb);
      DGC(A3, w3, ha, hb);
    }

    float a0 = A0.x + A0.y, a1 = A1.x + A1.y;
    float a2 = A2.x + A2.y, a3 = A3.x + A3.y;
#pragma unroll
    for (int m = 1; m < 64; m <<= 1) {
      a0 += __shfl_xor(a0, m);
      a1 += __shfl_xor(a1, m);
      a2 += __shfl_xor(a2, m);
      a3 += __shfl_xor(a3, m);
    }
    float sv = (lane == 0) ? a0 : (lane == 1) ? a1 : (lane == 2) ? a2 : a3;
    sv += xgv;
    const float av = (lane == 2) ? tanh_fast(sv) : sigmoid_fast(sv);
    const float iv = __shfl(av, 0);
    const float fv = __shfl(av, 1);
    const float gv = __shfl(av, 2);
    const float ov = __shfl(av, 3);
    if (lane == 0) {
      c_reg = fmaf(fv, c_reg, iv * gv);
      const float hn = ov * tanh_fast(c_reg);
      __hip_atomic_store(&out[(size_t)ts * HDIM + j], hn,
                         __ATOMIC_RELAXED, __HIP_MEMORY_SCOPE_AGENT);
    }
    // raw barrier (no vmcnt drain); then flag hint
    __builtin_amdgcn_s_barrier();
    if (t == 0)
      __hip_atomic_store(&flags[b], (unsigned)(ts + 1),
                         __ATOMIC_RELAXED, __HIP_MEMORY_SCOPE_AGENT);

    if (ts + 1 == S_LEN) break;

    // ---- wave0: poll 256 hint-flags (1 KB; reload only missing) ----
    if (wid == 0) {
      const unsigned want = (unsigned)(ts + 1);
      unsigned f0 = 0, f1 = 0, f2 = 0, f3 = 0;
      for (;;) {
        if (f0 < want) f0 = __hip_atomic_load(&flags[lane],       __ATOMIC_RELAXED, __HIP_MEMORY_SCOPE_AGENT);
        if (f1 < want) f1 = __hip_atomic_load(&flags[lane +  64], __ATOMIC_RELAXED, __HIP_MEMORY_SCOPE_AGENT);
        if (f2 < want) f2 = __hip_atomic_load(&flags[lane + 128], __ATOMIC_RELAXED, __HIP_MEMORY_SCOPE_AGENT);
        if (f3 < want) f3 = __hip_atomic_load(&flags[lane + 192], __ATOMIC_RELAXED, __HIP_MEMORY_SCOPE_AGENT);
        if (f0 >= want && f1 >= want && f2 >= want && f3 >= want) break;
        __builtin_amdgcn_s_sleep(1);
      }
    }
    __syncthreads();           // hint seen; all waves past dot -> hA/hB free
    // ---- bulk read h_ts: 2x8B/thread, per-element sentinel retry ----
    const unsigned long long* src =
        (const unsigned long long*)(out + (size_t)ts * HDIM);
    unsigned long long r0, r1;
    do {
      r0 = __hip_atomic_load(src + t, __ATOMIC_RELAXED,
                             __HIP_MEMORY_SCOPE_AGENT);
    } while (((unsigned)r0 == SENT) | ((unsigned)(r0 >> 32) == SENT));
    do {
      r1 = __hip_atomic_load(src + t + 512, __ATOMIC_RELAXED,
                             __HIP_MEMORY_SCOPE_AGENT);
    } while (((unsigned)r1 == SENT) | ((unsigned)(r1 >> 32) == SENT));
    {
      const int k0 = 2 * t, k1 = 2 * t + 1024;
      const int i0 = k0 >> 9, r0i = (k0 >> 3) & 63, e0 = k0 & 7;
      const int i1 = k1 >> 9, r1i = (k1 >> 3) & 63, e1 = k1 & 7;
      float* d0 = ((e0 & 4) ? hB : hA) + i0 * 256 + r0i * 4 + (e0 & 3);
      float* d1 = ((e1 & 4) ? hB : hA) + i1 * 256 + r1i * 4 + (e1 & 3);
      d0[0] = __uint_as_float((unsigned)r0);
      d0[1] = __uint_as_float((unsigned)(r0 >> 32));
      d1[0] = __uint_as_float((unsigned)r1);
      d1[1] = __uint_as_float((unsigned)(r1 >> 32));
    }
    __syncthreads();           // hA/hB = h_ts ready
  }
}

// =====================================================================
extern "C" void kernel_launch(void* const* d_in, const int* in_sizes, int n_in,
                              void* d_out, int out_size, void* d_ws, size_t ws_size,
                              hipStream_t stream) {
  const float* x   = (const float*)d_in[0];
  const float* Wih = (const float*)d_in[1];
  const float* Whh = (const float*)d_in[2];
  const float* bih = (const float*)d_in[3];
  const float* bhh = (const float*)d_in[4];
  const float* h0  = (const float*)d_in[5];
  const float* c0  = (const float*)d_in[6];
  float* out = (float*)d_out;

  // ws layout: [0,1KB) flags | [32KB, +64MB) xg bf16
  unsigned* flags = (unsigned*)d_ws;
  unsigned short* xg = (unsigned short*)((char*)d_ws + 32768);

  hipMemsetAsync(flags, 0, NB * sizeof(unsigned), stream);

  fill_sentinel<<<dim3(2048), 256, 0, stream>>>((unsigned long long*)out);
  gemm_xg_mfma<<<dim3(2048), 256, 0, stream>>>(x, Wih, bih, bhh, xg);

  void* args[] = {(void*)&xg, (void*)&Whh, (void*)&h0,
                  (void*)&c0, (void*)&out, (void*)&flags};
  hipLaunchCooperativeKernel((void*)lstm_scan, dim3(NB), dim3(TPB),
                             args, 131072 /* dynamic LDS: Wlds */, stream);
}